// Round 13
// baseline (189.008 us; speedup 1.0000x reference)
//
#include <hip/hip_runtime.h>
#include <hip/hip_bf16.h>
#include <cmath>

// Problem constants
#define BATCH   4096
#define NUNITS  1024
#define INSIZE  512
#define SIGSZ   6
#define KSIG    (NUNITS * SIGSZ)          // 6144
#define SAVED   (KSIG + NUNITS)           // 7168
#define KTOT    (INSIZE + KSIG + NUNITS)  // 7680
#define OUTW    (NUNITS * (SIGSZ + 1))    // 7168
#define NKT     (KTOT / 64)               // 120

// Workspace layout (ushort elements)
#define WS_AX 0LL
#define WS_AS 2097152LL
#define WS_AT 27262976LL
#define WS_BW 31457280LL
#define WS_BU 31981568LL
#define WS_ELEMS 39321600LL
#define WS_BYTES (WS_ELEMS * 2)           // 78,643,200

typedef __attribute__((ext_vector_type(8))) short bf16x8;
typedef __attribute__((ext_vector_type(8))) unsigned short u16x8;
typedef __attribute__((ext_vector_type(4))) unsigned short u16x4;
typedef __attribute__((ext_vector_type(4))) float f32x4;

__device__ __forceinline__ unsigned short f2bf(float f) {
    union { float f; unsigned int u; } c; c.f = f;
    unsigned int u = c.u;
    return (unsigned short)((u + 0x7FFFu + ((u >> 16) & 1u)) >> 16);  // RNE
}
__device__ __forceinline__ float bf2f(unsigned short h) {
    union { unsigned int u; float f; } c; c.u = ((unsigned int)h) << 16;
    return c.f;
}

// XOR-swizzled LDS index (ushort units), 128B (64 bf16) rows.
__device__ __forceinline__ int swz(int row, int bytecol) {
    return row * 64 + (((bytecol) ^ ((row & 7) << 4)) >> 1);
}

// ---------------- prepass: fp32 -> packed bf16 in ws ----------------
// nt LOADS (fp32 inputs are read-once; don't evict ws from L3);
// plain stores (ws must land and stay in L3 for the GEMM).
__global__ __launch_bounds__(256)
void prepack(const float* __restrict__ x, const float* __restrict__ sigs,
             const float* __restrict__ states, const float* __restrict__ Ww,
             const float* __restrict__ Uw, unsigned short* __restrict__ ws)
{
    const long long stride = (long long)gridDim.x * blockDim.x;
    for (long long p = (long long)blockIdx.x * blockDim.x + threadIdx.x;
         p < 4915200LL; p += stride) {
        const float* src; unsigned short* dst; long long o;
        if (p < 262144LL)       { src = x;      dst = ws + WS_AX; o = p; }
        else if (p < 3407872LL) { src = sigs;   dst = ws + WS_AS; o = p - 262144LL; }
        else if (p < 3932160LL) { src = states; dst = ws + WS_AT; o = p - 3407872LL; }
        else if (p < 3997696LL) { src = Ww;     dst = ws + WS_BW; o = p - 3932160LL; }
        else                    { src = Uw;     dst = ws + WS_BU; o = p - 3997696LL; }
        const f32x4 v0 = __builtin_nontemporal_load((const f32x4*)(src + o * 8));
        const f32x4 v1 = __builtin_nontemporal_load((const f32x4*)(src + o * 8) + 1);
        u16x8 h;
        h[0] = f2bf(v0[0]); h[1] = f2bf(v0[1]); h[2] = f2bf(v0[2]); h[3] = f2bf(v0[3]);
        h[4] = f2bf(v1[0]); h[5] = f2bf(v1[1]); h[6] = f2bf(v1[2]); h[7] = f2bf(v1[3]);
        *(u16x8*)(dst + o * 8) = h;
    }
}

// ---------------- main GEMM + fused sigjoin (R8 structure, verbatim) ----------------
// 128x128 tile, BK=64, 1024 threads = 16 waves: 2(M) x 4(N) x 2(K-split).
// Wave tile 64x32 per K-half (4 ds_read A + 2 ds_read B -> 8 MFMA).
// Grid 256 = 1 block/CU; bn = blockIdx&7 = XCD id (B-slice L2-resident).
// 3-deep LDS ring (96 KB), counted vmcnt(2), one raw s_barrier per iter.
// Epilogue: raw(+bias) -> padded 128x132 fp32 LDS tile (K-split merged),
// then dense float4 store pass; all use-once epilogue streams nt-loaded.
#define GLD_LDS(G, L) __builtin_amdgcn_global_load_lds(                        \
        (const __attribute__((address_space(1))) unsigned int*)(G),           \
        (__attribute__((address_space(3))) unsigned int*)(L), 16, 0, 0)

__global__ __launch_bounds__(1024, 1)
void rsig_gemm(const unsigned short* __restrict__ ws,
               const float* __restrict__ states,
               const float* __restrict__ Wb,
               const float* __restrict__ Ub,
               const float* __restrict__ lt,
               float* __restrict__ out)
{
    // ring: per buffer (32 KB): A tile [0,8192), B tile [8192,16384) ushorts.
    // epilogue reuses the same LDS as a 128x132 fp32 raw tile (67.6 KB).
    __shared__ unsigned short lds[3 * 16384];   // 96 KB

    const int t  = threadIdx.x;
    const int bn = blockIdx.x & 7;   // natural round-robin: same bn -> same XCD
    const int bm = blockIdx.x >> 3;  // 0..31

    const int lane = t & 63;
    const int w    = t >> 6;        // 0..15
    const int wm   = w >> 3;        // M half (0..1)
    const int wn   = (w >> 1) & 3;  // N quarter (0..3)
    const int wk   = w & 1;         // K slot (0: K 0..31 of tile, 1: 32..63)
    const int lr   = lane & 15;
    const int lg   = lane >> 4;

    const unsigned short* wsAx = ws + WS_AX;
    const unsigned short* wsAs = ws + WS_AS;
    const unsigned short* wsAt = ws + WS_AT;
    const unsigned short* wsBw = ws + WS_BW;
    const unsigned short* wsBu = ws + WS_BU;

    // staging: 16 A-groups + 16 B-groups of (8 rows x 64 cols); 1 A + 1 B per wave
    const int sRow = lane >> 3;
    const int sCol = 8 * ((lane & 7) ^ sRow);   // pre-swizzled source col (elems)

    f32x4 acc[4][2];
#pragma unroll
    for (int m = 0; m < 4; ++m)
#pragma unroll
        for (int n = 0; n < 2; ++n)
            acc[m][n] = (f32x4)0.f;

    // 2 gld_lds per wave per STAGE (1 A-group + 1 B-group)
#define STAGE(BUF, KT)                                                                  \
    {                                                                                   \
        const int kt_ = (KT);                                                           \
        const unsigned short* abase; int astr, koff;                                    \
        if (kt_ < 8)        { abase = wsAx; astr = INSIZE; koff = kt_ * 64; }           \
        else if (kt_ < 104) { abase = wsAs; astr = KSIG;   koff = kt_ * 64 - 512; }     \
        else                { abase = wsAt; astr = NUNITS; koff = kt_ * 64 - 6656; }    \
        const unsigned short* bbase; int bstr, koffb;                                   \
        if (kt_ < 8)        { bbase = wsBw; bstr = INSIZE; koffb = kt_ * 64; }          \
        else                { bbase = wsBu; bstr = SAVED;  koffb = kt_ * 64 - 512; }    \
        unsigned short* base = &lds[(BUF) * 16384];                                     \
        const unsigned short* ga = abase                                                \
            + (size_t)(bm * 128 + w * 8 + sRow) * astr + koff + sCol;                   \
        GLD_LDS(ga, base + w * 512);                                                    \
        const unsigned short* gb = bbase                                                \
            + (size_t)(bn * 128 + w * 8 + sRow) * bstr + koffb + sCol;                  \
        GLD_LDS(gb, base + 8192 + w * 512);                                             \
    }

    // Prologue: 2 tiles in flight (4 loads/wave outstanding)
    STAGE(0, 0);
    STAGE(1, 1);

    int cur = 0;
    for (int kt = 0; kt < NKT; ++kt) {
        if (kt < NKT - 1) { asm volatile("s_waitcnt vmcnt(2)" ::: "memory"); }
        else              { asm volatile("s_waitcnt vmcnt(0)" ::: "memory"); }
        __builtin_amdgcn_s_barrier();
        __builtin_amdgcn_sched_barrier(0);

        if (kt + 2 < NKT) {
            int nb = cur + 2; if (nb >= 3) nb -= 3;
            STAGE(nb, kt + 2);   // overwrites buf[(kt-1)%3]: readers done pre-barrier
        }

        {
            const unsigned short* aT = &lds[cur * 16384];
            const unsigned short* bT = aT + 8192;
            bf16x8 af[4], bfr[2];
#pragma unroll
            for (int m = 0; m < 4; ++m)
                af[m] = *(const bf16x8*)&aT[swz(wm * 64 + m * 16 + lr, wk * 64 + lg * 16)];
#pragma unroll
            for (int n = 0; n < 2; ++n)
                bfr[n] = *(const bf16x8*)&bT[swz(wn * 32 + n * 16 + lr, wk * 64 + lg * 16)];
#pragma unroll
            for (int m = 0; m < 4; ++m)
#pragma unroll
                for (int n = 0; n < 2; ++n)
                    acc[m][n] = __builtin_amdgcn_mfma_f32_16x16x32_bf16(af[m], bfr[n], acc[m][n], 0, 0, 0);
        }

        cur = (cur == 2) ? 0 : cur + 1;
    }

    // all waves done reading the last ring buffer before LDS reuse
    __syncthreads();

    // ---- Phase 1: raw(+bias) -> padded LDS tile; K-split merged in-place ----
    float* rawt = (float*)lds;            // 128 rows x 132 floats
    if (wk == 0) {
#pragma unroll
        for (int n = 0; n < 2; ++n) {
            const int cc = wn * 32 + n * 16 + lr;
            const int ug = bn * 128 + cc;
            const float bias = Wb[ug] + Ub[ug];
#pragma unroll
            for (int m = 0; m < 4; ++m) {
                const int rr = wm * 64 + m * 16 + lg * 4;
#pragma unroll
                for (int i = 0; i < 4; ++i)
                    rawt[(rr + i) * 132 + cc] = acc[m][n][i] + bias;
            }
        }
    }
    __syncthreads();
    if (wk == 1) {
#pragma unroll
        for (int n = 0; n < 2; ++n) {
            const int cc = wn * 32 + n * 16 + lr;
#pragma unroll
            for (int m = 0; m < 4; ++m) {
                const int rr = wm * 64 + m * 16 + lg * 4;
#pragma unroll
                for (int i = 0; i < 4; ++i)
                    rawt[(rr + i) * 132 + cc] += acc[m][n][i];
            }
        }
    }
    __syncthreads();

    // ---- Phase 2: dense float4 store pass ----
    // per row: c in [0,192) -> sig float4; [192,224) -> raw float4.
    // All global reads here are use-once -> nontemporal (protect ws/A in L3).
    const float tl = expf(lt[0]);
    const int r0 = t >> 8;      // 0..3
    const int c  = t & 255;

    for (int pass = 0; pass < 32; ++pass) {
        const int r = pass * 4 + r0;
        const long long b = (long long)bm * 128 + r;
        if (c < 192) {
            const int u  = (2 * c) / 3;
            const int cs = c % 3;
            const unsigned short* srow = wsAs + b * KSIG + bn * 768;
            const float* strow = states + b * NUNITS + bn * 128;
            const u16x4 sin = __builtin_nontemporal_load((const u16x4*)(srow + c * 4));
            const float e0 = bf2f(sin[0]), e1 = bf2f(sin[1]);
            const float e2 = bf2f(sin[2]), e3 = bf2f(sin[3]);
            float4 o;
            if (cs == 0) {                 // cols 6u+0..3: s0,s1,s2,s3
                const float d = rawt[r * 132 + u] - __builtin_nontemporal_load(strow + u);
                o.x = e0 + d;
                o.y = e1 + tl;
                o.z = e2 + d  * (0.5f * d  + e0);
                o.w = e3 + tl * (0.5f * d  + e0);
            } else if (cs == 1) {          // cols 6u+4,5, 6(u+1)+0,1
                const float d  = rawt[r * 132 + u]     - __builtin_nontemporal_load(strow + u);
                const float dn = rawt[r * 132 + u + 1] - __builtin_nontemporal_load(strow + u + 1);
                const float s1 = bf2f(__builtin_nontemporal_load(srow + u * 6 + 1));
                o.x = e0 + d  * (0.5f * tl + s1);
                o.y = e1 + tl * (0.5f * tl + s1);
                o.z = e2 + dn;
                o.w = e3 + tl;
            } else {                       // cols 6u+2..5: s2,s3,s4,s5
                const float d = rawt[r * 132 + u] - __builtin_nontemporal_load(strow + u);
                const unsigned int sv = __builtin_nontemporal_load((const unsigned int*)(srow + u * 6));
                const float s0 = bf2f((unsigned short)(sv & 0xffffu));
                const float s1 = bf2f((unsigned short)(sv >> 16));
                o.x = e0 + d  * (0.5f * d  + s0);
                o.y = e1 + tl * (0.5f * d  + s0);
                o.z = e2 + d  * (0.5f * tl + s1);
                o.w = e3 + tl * (0.5f * tl + s1);
            }
            *(float4*)(out + b * OUTW + bn * 768 + c * 4) = o;
        } else if (c < 224) {
            const int cc = (c - 192) * 4;
            const float4 rv = *(const float4*)&rawt[r * 132 + cc];
            *(float4*)(out + b * OUTW + KSIG + bn * 128 + cc) = rv;
        }
    }
#undef STAGE
}

extern "C" void kernel_launch(void* const* d_in, const int* in_sizes, int n_in,
                              void* d_out, int out_size, void* d_ws, size_t ws_size,
                              hipStream_t stream) {
    const float* x      = (const float*)d_in[0];
    const float* sigs   = (const float*)d_in[1];
    const float* states = (const float*)d_in[2];
    const float* Ww     = (const float*)d_in[3];
    const float* Wb     = (const float*)d_in[4];
    const float* Uw     = (const float*)d_in[5];
    const float* Ub     = (const float*)d_in[6];
    const float* lt     = (const float*)d_in[7];
    float* out = (float*)d_out;

    unsigned short* ws = (unsigned short*)d_ws;
    hipLaunchKernelGGL(prepack, dim3(2048), dim3(256), 0, stream,
                       x, sigs, states, Ww, Uw, ws);
    hipLaunchKernelGGL(rsig_gemm, dim3(256), dim3(1024), 0, stream,
                       ws, states, Wb, Ub, lt, out);
}

// Round 14
// 147.371 us; speedup vs baseline: 1.2825x; 1.2825x over previous
//
#include <hip/hip_runtime.h>
#include <hip/hip_bf16.h>
#include <cmath>

// Problem constants
#define BATCH   4096
#define NUNITS  1024
#define INSIZE  512
#define SIGSZ   6
#define KSIG    (NUNITS * SIGSZ)          // 6144
#define SAVED   (KSIG + NUNITS)           // 7168
#define KTOT    (INSIZE + KSIG + NUNITS)  // 7680
#define OUTW    (NUNITS * (SIGSZ + 1))    // 7168
#define NKT     (KTOT / 64)               // 120

// Workspace layout (ushort elements)
#define WS_AX 0LL
#define WS_AS 2097152LL
#define WS_AT 27262976LL
#define WS_BW 31457280LL
#define WS_BU 31981568LL
#define WS_ELEMS 39321600LL
#define WS_BYTES (WS_ELEMS * 2)           // 78,643,200

typedef __attribute__((ext_vector_type(8))) short bf16x8;
typedef __attribute__((ext_vector_type(8))) unsigned short u16x8;
typedef __attribute__((ext_vector_type(4))) float f32x4;

__device__ __forceinline__ unsigned short f2bf(float f) {
    union { float f; unsigned int u; } c; c.f = f;
    unsigned int u = c.u;
    return (unsigned short)((u + 0x7FFFu + ((u >> 16) & 1u)) >> 16);  // RNE
}
__device__ __forceinline__ float bf2f(unsigned short h) {
    union { unsigned int u; float f; } c; c.u = ((unsigned int)h) << 16;
    return c.f;
}

// XOR-swizzled LDS index (ushort units), 128B (64 bf16) rows.
__device__ __forceinline__ int swz(int row, int bytecol) {
    return row * 64 + (((bytecol) ^ ((row & 7) << 4)) >> 1);
}

// ---------------- prepass: fp32 -> packed bf16 in ws ----------------
// nt LOADS only (fp32 inputs are read-once); plain stores (ws must stay in L3).
__global__ __launch_bounds__(256)
void prepack(const float* __restrict__ x, const float* __restrict__ sigs,
             const float* __restrict__ states, const float* __restrict__ Ww,
             const float* __restrict__ Uw, unsigned short* __restrict__ ws)
{
    const long long stride = (long long)gridDim.x * blockDim.x;
    for (long long p = (long long)blockIdx.x * blockDim.x + threadIdx.x;
         p < 4915200LL; p += stride) {
        const float* src; unsigned short* dst; long long o;
        if (p < 262144LL)       { src = x;      dst = ws + WS_AX; o = p; }
        else if (p < 3407872LL) { src = sigs;   dst = ws + WS_AS; o = p - 262144LL; }
        else if (p < 3932160LL) { src = states; dst = ws + WS_AT; o = p - 3407872LL; }
        else if (p < 3997696LL) { src = Ww;     dst = ws + WS_BW; o = p - 3932160LL; }
        else                    { src = Uw;     dst = ws + WS_BU; o = p - 3997696LL; }
        const f32x4 v0 = __builtin_nontemporal_load((const f32x4*)(src + o * 8));
        const f32x4 v1 = __builtin_nontemporal_load((const f32x4*)(src + o * 8) + 1);
        u16x8 h;
        h[0] = f2bf(v0[0]); h[1] = f2bf(v0[1]); h[2] = f2bf(v0[2]); h[3] = f2bf(v0[3]);
        h[4] = f2bf(v1[0]); h[5] = f2bf(v1[1]); h[6] = f2bf(v1[2]); h[7] = f2bf(v1[3]);
        *(u16x8*)(dst + o * 8) = h;
    }
}

// ---------------- main GEMM + fused sigjoin (R8 structure) ----------------
// 128x128 tile, BK=64, 1024 threads = 16 waves: 2(M) x 4(N) x 2(K-split).
// 3-deep LDS ring (96 KB), counted vmcnt(2), one raw s_barrier per iter.
// NEW: states stash — A-tiles kt0=104+2*bn, kt0+1 (which ARE this block's
// epilogue states slice) are copied ring->stash (32 KB LDS) when they land;
// the epilogue reads ps from LDS instead of scalar global fp32 loads.
// Epilogue: raw(+bias) -> padded 128x132 fp32 LDS tile, dense float4 stores.
#define GLD_LDS(G, L) __builtin_amdgcn_global_load_lds(                        \
        (const __attribute__((address_space(1))) unsigned int*)(G),           \
        (__attribute__((address_space(3))) unsigned int*)(L), 16, 0, 0)

__global__ __launch_bounds__(1024, 1)
void rsig_gemm(const unsigned short* __restrict__ ws,
               const float* __restrict__ Wb,
               const float* __restrict__ Ub,
               const float* __restrict__ lt,
               float* __restrict__ out)
{
    // ring: 3 x (A 16KB + B 16KB) = 96 KB; stash: 2 x 16 KB states tiles.
    // epilogue rawt (67.6 KB) reuses ring space only; stash untouched.
    __shared__ unsigned short lds[3 * 16384 + 16384];   // 128 KB

    const int t  = threadIdx.x;
    const int bn = blockIdx.x & 7;   // natural round-robin: same bn -> same XCD
    const int bm = blockIdx.x >> 3;  // 0..31

    const int lane = t & 63;
    const int w    = t >> 6;        // 0..15
    const int wm   = w >> 3;        // M half (0..1)
    const int wn   = (w >> 1) & 3;  // N quarter (0..3)
    const int wk   = w & 1;         // K slot (0: K 0..31 of tile, 1: 32..63)
    const int lr   = lane & 15;
    const int lg   = lane >> 4;

    const unsigned short* wsAx = ws + WS_AX;
    const unsigned short* wsAs = ws + WS_AS;
    const unsigned short* wsAt = ws + WS_AT;
    const unsigned short* wsBw = ws + WS_BW;
    const unsigned short* wsBu = ws + WS_BU;

    unsigned short* stash = &lds[3 * 16384];
    const int kt0 = 104 + bn * 2;   // A-tiles holding this block's states slice

    // staging: 16 A-groups + 16 B-groups of (8 rows x 64 cols); 1 A + 1 B per wave
    const int sRow = lane >> 3;
    const int sCol = 8 * ((lane & 7) ^ sRow);   // pre-swizzled source col (elems)

    f32x4 acc[4][2];
#pragma unroll
    for (int m = 0; m < 4; ++m)
#pragma unroll
        for (int n = 0; n < 2; ++n)
            acc[m][n] = (f32x4)0.f;

    // 2 gld_lds per wave per STAGE (1 A-group + 1 B-group)
#define STAGE(BUF, KT)                                                                  \
    {                                                                                   \
        const int kt_ = (KT);                                                           \
        const unsigned short* abase; int astr, koff;                                    \
        if (kt_ < 8)        { abase = wsAx; astr = INSIZE; koff = kt_ * 64; }           \
        else if (kt_ < 104) { abase = wsAs; astr = KSIG;   koff = kt_ * 64 - 512; }     \
        else                { abase = wsAt; astr = NUNITS; koff = kt_ * 64 - 6656; }    \
        const unsigned short* bbase; int bstr, koffb;                                   \
        if (kt_ < 8)        { bbase = wsBw; bstr = INSIZE; koffb = kt_ * 64; }          \
        else                { bbase = wsBu; bstr = SAVED;  koffb = kt_ * 64 - 512; }    \
        unsigned short* base = &lds[(BUF) * 16384];                                     \
        const unsigned short* ga = abase                                                \
            + (size_t)(bm * 128 + w * 8 + sRow) * astr + koff + sCol;                   \
        GLD_LDS(ga, base + w * 512);                                                    \
        const unsigned short* gb = bbase                                                \
            + (size_t)(bn * 128 + w * 8 + sRow) * bstr + koffb + sCol;                  \
        GLD_LDS(gb, base + 8192 + w * 512);                                             \
    }

    // Prologue: 2 tiles in flight (4 loads/wave outstanding)
    STAGE(0, 0);
    STAGE(1, 1);

    int cur = 0;
    for (int kt = 0; kt < NKT; ++kt) {
        if (kt < NKT - 1) { asm volatile("s_waitcnt vmcnt(2)" ::: "memory"); }
        else              { asm volatile("s_waitcnt vmcnt(0)" ::: "memory"); }
        __builtin_amdgcn_s_barrier();
        __builtin_amdgcn_sched_barrier(0);

        if (kt + 2 < NKT) {
            int nb = cur + 2; if (nb >= 3) nb -= 3;
            STAGE(nb, kt + 2);   // overwrites buf[(kt-1)%3]: readers done pre-barrier
        }

        // states stash: this tile's A half IS our epilogue states slice
        if (kt == kt0) {
            const u16x8 v = *(const u16x8*)&lds[cur * 16384 + t * 8];
            *(u16x8*)&stash[t * 8] = v;
        } else if (kt == kt0 + 1) {
            const u16x8 v = *(const u16x8*)&lds[cur * 16384 + t * 8];
            *(u16x8*)&stash[8192 + t * 8] = v;
        }

        {
            const unsigned short* aT = &lds[cur * 16384];
            const unsigned short* bT = aT + 8192;
            bf16x8 af[4], bfr[2];
#pragma unroll
            for (int m = 0; m < 4; ++m)
                af[m] = *(const bf16x8*)&aT[swz(wm * 64 + m * 16 + lr, wk * 64 + lg * 16)];
#pragma unroll
            for (int n = 0; n < 2; ++n)
                bfr[n] = *(const bf16x8*)&bT[swz(wn * 32 + n * 16 + lr, wk * 64 + lg * 16)];
#pragma unroll
            for (int m = 0; m < 4; ++m)
#pragma unroll
                for (int n = 0; n < 2; ++n)
                    acc[m][n] = __builtin_amdgcn_mfma_f32_16x16x32_bf16(af[m], bfr[n], acc[m][n], 0, 0, 0);
        }

        cur = (cur == 2) ? 0 : cur + 1;
    }

    // all waves done reading the last ring buffer before LDS reuse
    __syncthreads();

    // ---- Phase 1: raw(+bias) -> padded LDS tile; K-split merged in-place ----
    float* rawt = (float*)lds;            // 128 rows x 132 floats (67.6 KB)
    if (wk == 0) {
#pragma unroll
        for (int n = 0; n < 2; ++n) {
            const int cc = wn * 32 + n * 16 + lr;
            const int ug = bn * 128 + cc;
            const float bias = Wb[ug] + Ub[ug];
#pragma unroll
            for (int m = 0; m < 4; ++m) {
                const int rr = wm * 64 + m * 16 + lg * 4;
#pragma unroll
                for (int i = 0; i < 4; ++i)
                    rawt[(rr + i) * 132 + cc] = acc[m][n][i] + bias;
            }
        }
    }
    __syncthreads();
    if (wk == 1) {
#pragma unroll
        for (int n = 0; n < 2; ++n) {
            const int cc = wn * 32 + n * 16 + lr;
#pragma unroll
            for (int m = 0; m < 4; ++m) {
                const int rr = wm * 64 + m * 16 + lg * 4;
#pragma unroll
                for (int i = 0; i < 4; ++i)
                    rawt[(rr + i) * 132 + cc] += acc[m][n][i];
            }
        }
    }
    __syncthreads();

    // ---- Phase 2: dense float4 store pass ----
    // per row: c in [0,192) -> sig float4; [192,224) -> raw float4.
    // ps comes from the LDS stash (bf16), layout = gld_lds linear order:
    //   tile = cc>>6, q = r&7, pos = (r>>3)*512 + q*64 + (((cc&63)>>3 ^ q)<<3) + (cc&7)
    const float tl = expf(lt[0]);
    const int r0 = t >> 8;      // 0..3
    const int c  = t & 255;

#define PS(R, CC) bf2f(stash[((CC) >> 6) * 8192 + ((R) >> 3) * 512 + ((R) & 7) * 64 \
                            + (((((CC) & 63) >> 3) ^ ((R) & 7)) << 3) + ((CC) & 7)])

    for (int pass = 0; pass < 32; ++pass) {
        const int r = pass * 4 + r0;
        const long long b = (long long)bm * 128 + r;
        if (c < 192) {
            const int u  = (2 * c) / 3;
            const int cs = c % 3;
            const unsigned short* srow = wsAs + b * KSIG + bn * 768;
            const ushort4 sin = *(const ushort4*)(srow + c * 4);
            const float e0 = bf2f(sin.x), e1 = bf2f(sin.y);
            const float e2 = bf2f(sin.z), e3 = bf2f(sin.w);
            float4 o;
            if (cs == 0) {                 // cols 6u+0..3: s0,s1,s2,s3
                const float d = rawt[r * 132 + u] - PS(r, u);
                o.x = e0 + d;
                o.y = e1 + tl;
                o.z = e2 + d  * (0.5f * d  + e0);
                o.w = e3 + tl * (0.5f * d  + e0);
            } else if (cs == 1) {          // cols 6u+4,5, 6(u+1)+0,1
                const float d  = rawt[r * 132 + u]     - PS(r, u);
                const float dn = rawt[r * 132 + u + 1] - PS(r, u + 1);
                const float s1 = bf2f(srow[u * 6 + 1]);
                o.x = e0 + d  * (0.5f * tl + s1);
                o.y = e1 + tl * (0.5f * tl + s1);
                o.z = e2 + dn;
                o.w = e3 + tl;
            } else {                       // cols 6u+2..5: s2,s3,s4,s5
                const float d = rawt[r * 132 + u] - PS(r, u);
                const unsigned int sv = *(const unsigned int*)(srow + u * 6);
                const float s0 = bf2f((unsigned short)(sv & 0xffffu));
                const float s1 = bf2f((unsigned short)(sv >> 16));
                o.x = e0 + d  * (0.5f * d  + s0);
                o.y = e1 + tl * (0.5f * d  + s0);
                o.z = e2 + d  * (0.5f * tl + s1);
                o.w = e3 + tl * (0.5f * tl + s1);
            }
            *(float4*)(out + b * OUTW + bn * 768 + c * 4) = o;
        } else if (c < 224) {
            const int cc = (c - 192) * 4;
            const float4 rv = *(const float4*)&rawt[r * 132 + cc];
            *(float4*)(out + b * OUTW + KSIG + bn * 128 + cc) = rv;
        }
    }
#undef PS
#undef STAGE
}

extern "C" void kernel_launch(void* const* d_in, const int* in_sizes, int n_in,
                              void* d_out, int out_size, void* d_ws, size_t ws_size,
                              hipStream_t stream) {
    const float* x      = (const float*)d_in[0];
    const float* sigs   = (const float*)d_in[1];
    const float* states = (const float*)d_in[2];
    const float* Ww     = (const float*)d_in[3];
    const float* Wb     = (const float*)d_in[4];
    const float* Uw     = (const float*)d_in[5];
    const float* Ub     = (const float*)d_in[6];
    const float* lt     = (const float*)d_in[7];
    float* out = (float*)d_out;

    unsigned short* ws = (unsigned short*)d_ws;
    hipLaunchKernelGGL(prepack, dim3(2048), dim3(256), 0, stream,
                       x, sigs, states, Ww, Uw, ws);
    hipLaunchKernelGGL(rsig_gemm, dim3(256), dim3(1024), 0, stream,
                       ws, Wb, Ub, lt, out);
}